// Round 2
// baseline (498.349 us; speedup 1.0000x reference)
//
#include <hip/hip_runtime.h>

typedef _Float16 half_t;
typedef __attribute__((ext_vector_type(8))) _Float16 f16x8;
typedef __attribute__((ext_vector_type(4))) float f32x4;

#define DM 256
#define NH 8
#define HD 32
#define NN 256
#define NB 2
#define JT 32
#define KC 64

// ---------------- LayerNorm (one row per block, 256 threads) ----------------
__global__ __launch_bounds__(256) void k_ln(const float* __restrict__ in,
                                            const float* __restrict__ g,
                                            const float* __restrict__ be,
                                            float* __restrict__ out) {
  int row = blockIdx.x, t = threadIdx.x;
  float v = in[(size_t)row * DM + t];
  float s = v, q = v * v;
#pragma unroll
  for (int m = 1; m <= 32; m <<= 1) {
    s += __shfl_xor(s, m, 64);
    q += __shfl_xor(q, m, 64);
  }
  __shared__ float as_[4], aq_[4];
  int w = t >> 6, l = t & 63;
  if (l == 0) { as_[w] = s; aq_[w] = q; }
  __syncthreads();
  s = as_[0] + as_[1] + as_[2] + as_[3];
  q = aq_[0] + aq_[1] + aq_[2] + aq_[3];
  float mu = s * (1.0f / DM);
  float var = q * (1.0f / DM) - mu * mu;
  out[(size_t)row * DM + t] = (v - mu) * rsqrtf(var + 1e-5f) * g[t] + be[t];
}

// ---------------- W^T in f16 (MFMA A operand: WT[c,k] = W[k,c]) ------------
__global__ __launch_bounds__(256) void k_wt16(const float* __restrict__ W,
                                              half_t* __restrict__ WT) {
  int c = blockIdx.x, t = threadIdx.x;
  WT[c * DM + t] = (half_t)W[t * DM + c];
}

// ---------------- node projection: nqv = xs@W + b --------------------------
__global__ __launch_bounds__(256) void k_proj(const float* __restrict__ xin,
                                              const float* __restrict__ W,
                                              const float* __restrict__ bias,
                                              float* __restrict__ out) {
  __shared__ float sx[2][DM];
  int t = threadIdx.x, r0 = blockIdx.x * 2;
#pragma unroll
  for (int r = 0; r < 2; ++r) sx[r][t] = xin[(size_t)(r0 + r) * DM + t];
  __syncthreads();
  float a0 = 0.f, a1 = 0.f;
#pragma unroll 8
  for (int k = 0; k < DM; ++k) {
    float wv = W[k * DM + t];
    a0 += sx[0][k] * wv;
    a1 += sx[1][k] * wv;
  }
  float bb = bias[t];
  out[(size_t)r0 * DM + t] = a0 + bb;
  out[(size_t)(r0 + 1) * DM + t] = a1 + bb;
}

// ---------------- fused edge proj + scores ---------------------------------
// Q~[j,:] = (edge[j]+x_i)@W + 2b ; K~[j,:] = (edge[j]+x_j)@W + 2b
// score[h,j] = (1/sqrt32) * sum_{c in h} Q~ K~ ; out = 10*tanh(.)
// Swapped MFMA (A=WT rows=c, B=edge rows=j) -> D[c,j]; head-sum = in-lane
// fma + 2 shfl. grid 4096 = (b, i, jb). LDS 40KB: A1 4K | A2 4K | WT 32K.
__global__ __launch_bounds__(256, 4) void k_edge_scores(
    const float* __restrict__ edges, const half_t* __restrict__ WT,
    const float* __restrict__ xs, const float* __restrict__ bias,
    float* __restrict__ scores) {
  __shared__ __align__(16) char smem[40960];
  const int tid = threadIdx.x;
  const int l = tid & 63;
  const int w = tid >> 6;
  const int idx = blockIdx.x;
  const int jb = idx & 7;
  const int i = (idx >> 3) & (NN - 1);
  const int b = idx >> 11;
  const int j0 = jb * JT;

  f32x4 accq[4][2], acck[4][2];
#pragma unroll
  for (int ct = 0; ct < 4; ++ct) {
    f32x4 bv = *(const f32x4*)(bias + w * 64 + ct * 16 + (l >> 4) * 4);
    f32x4 iv = {2.f * bv[0], 2.f * bv[1], 2.f * bv[2], 2.f * bv[3]};
#pragma unroll
    for (int jt = 0; jt < 2; ++jt) { accq[ct][jt] = iv; acck[ct][jt] = iv; }
  }

  const float* eg = edges + ((size_t)(b * NN + i) * NN + j0) * DM;
  const float* xb = xs + (size_t)b * NN * DM;
  const float* xi = xb + (size_t)i * DM;
  const int f4 = tid & 15, row0 = tid >> 4;

  // prefetch chunk 0 (edge + x_j + x_i) into registers
  f32x4 pe[2], pxj[2], pxi[2];
#pragma unroll
  for (int q = 0; q < 2; ++q) {
    int row = row0 + q * 16;
    pe[q] = *(const f32x4*)(eg + row * DM + f4 * 4);
    pxj[q] = *(const f32x4*)(xb + (size_t)(j0 + row) * DM + f4 * 4);
    pxi[q] = *(const f32x4*)(xi + f4 * 4);
  }

  for (int kc = 0; kc < 4; ++kc) {
    // WT chunk -> LDS direct (linear dest, inverse-swizzled global source)
    {
      const char* wtb = (const char*)WT;
#pragma unroll
      for (int q = 0; q < 8; ++q) {
        int ub = (w * 8 + q) * 64;
        int cc = (ub + l) >> 3;
        int ss = l & 7;
        const void* src = wtb + cc * 512 + kc * 128 + ((ss ^ (cc & 7)) * 16);
        __builtin_amdgcn_global_load_lds(
            (const __attribute__((address_space(1))) unsigned int*)src,
            (__attribute__((address_space(3))) unsigned int*)(smem + 8192 + ub * 16),
            16, 0, 0);
      }
    }
    // convert + swizzled write of A1 (edge+x_i) and A2 (edge+x_j)
#pragma unroll
    for (int q = 0; q < 2; ++q) {
      int row = row0 + q * 16;
      union { unsigned long long u; half_t h[4]; } a1, a2;
#pragma unroll
      for (int z = 0; z < 4; ++z) {
        a1.h[z] = (half_t)(pe[q][z] + pxi[q][z]);
        a2.h[z] = (half_t)(pe[q][z] + pxj[q][z]);
      }
      int off = (row * 128 + f4 * 8) ^ ((row & 7) << 4);
      *(unsigned long long*)(smem + off) = a1.u;
      *(unsigned long long*)(smem + 4096 + off) = a2.u;
    }
    __syncthreads();  // drains vmcnt (WT in LDS) + lgkm (A writes)
    // prefetch next chunk -- overlaps the MFMA phase below
    if (kc < 3) {
#pragma unroll
      for (int q = 0; q < 2; ++q) {
        int row = row0 + q * 16;
        pe[q] = *(const f32x4*)(eg + row * DM + (kc + 1) * KC + f4 * 4);
        pxj[q] = *(const f32x4*)(xb + (size_t)(j0 + row) * DM + (kc + 1) * KC + f4 * 4);
        pxi[q] = *(const f32x4*)(xi + (kc + 1) * KC + f4 * 4);
      }
    }
#pragma unroll
    for (int ks = 0; ks < 2; ++ks) {
      f16x8 fq[2], fk[2];
#pragma unroll
      for (int jt = 0; jt < 2; ++jt) {
        int r = jt * 16 + (l & 15);
        int off = (r * 128 + ks * 64 + ((l >> 4) * 16)) ^ ((r & 7) << 4);
        fq[jt] = *(const f16x8*)(smem + off);
        fk[jt] = *(const f16x8*)(smem + 4096 + off);
      }
#pragma unroll
      for (int ct = 0; ct < 4; ++ct) {
        int c = w * 64 + ct * 16 + (l & 15);
        int off = (c * 128 + ks * 64 + ((l >> 4) * 16)) ^ ((c & 7) << 4);
        f16x8 wf = *(const f16x8*)(smem + 8192 + off);
#pragma unroll
        for (int jt = 0; jt < 2; ++jt) {
          accq[ct][jt] = __builtin_amdgcn_mfma_f32_16x16x32_f16(wf, fq[jt], accq[ct][jt], 0, 0, 0);
          acck[ct][jt] = __builtin_amdgcn_mfma_f32_16x16x32_f16(wf, fk[jt], acck[ct][jt], 0, 0, 0);
        }
      }
    }
    __syncthreads();
  }

  const float scale = 0.17677669529663687f;  // 1/sqrt(32)
#pragma unroll
  for (int a = 0; a < 2; ++a) {
#pragma unroll
    for (int jt = 0; jt < 2; ++jt) {
      float s = 0.f;
#pragma unroll
      for (int u = 0; u < 2; ++u) {
        int ct = a * 2 + u;
#pragma unroll
        for (int rr = 0; rr < 4; ++rr) s += accq[ct][jt][rr] * acck[ct][jt][rr];
      }
      s += __shfl_xor(s, 16, 64);
      s += __shfl_xor(s, 32, 64);
      float sc = 10.0f * tanhf(s * scale);
      if (l < 16) {
        int h = w * 2 + a;
        int jg = j0 + jt * 16 + l;
        scores[(((size_t)(b * NH) + h) * NN + i) * NN + jg] = sc;
      }
    }
  }
}

// ---------------- fused softmax + attn@V (block per (b,i)) -----------------
__global__ __launch_bounds__(256) void k_smax_av(const float* __restrict__ scores,
                                                 const float* __restrict__ nqv,
                                                 float* __restrict__ ao) {
  __shared__ float sp[NH * NN];
  int t = threadIdx.x;
  int b = blockIdx.x >> 8, i = blockIdx.x & 255;
#pragma unroll
  for (int p = 0; p < 8; ++p) {
    int idx = p * 256 + t;
    sp[idx] = scores[(((size_t)(b * NH) + (idx >> 8)) * NN + i) * NN + (idx & 255)];
  }
  __syncthreads();
  int w = t >> 6, l = t & 63;
#pragma unroll
  for (int hh = 0; hh < 2; ++hh) {
    int h = w * 2 + hh;
    f32x4 v = *(f32x4*)(sp + h * NN + l * 4);
    float m = fmaxf(fmaxf(v[0], v[1]), fmaxf(v[2], v[3]));
#pragma unroll
    for (int mm = 1; mm <= 32; mm <<= 1) m = fmaxf(m, __shfl_xor(m, mm, 64));
    v[0] = __expf(v[0] - m); v[1] = __expf(v[1] - m);
    v[2] = __expf(v[2] - m); v[3] = __expf(v[3] - m);
    float s = v[0] + v[1] + v[2] + v[3];
#pragma unroll
    for (int mm = 1; mm <= 32; mm <<= 1) s += __shfl_xor(s, mm, 64);
    float inv = 1.0f / s;
    v[0] *= inv; v[1] *= inv; v[2] *= inv; v[3] *= inv;
    *(f32x4*)(sp + h * NN + l * 4) = v;
  }
  __syncthreads();
  float acc = 0.f;
  int h = t >> 5;
  const float* vb = nqv + (size_t)b * NN * DM;
#pragma unroll 4
  for (int j = 0; j < NN; ++j) acc += sp[h * 256 + j] * vb[(size_t)j * DM + t];
  ao[((size_t)(b * NN) + i) * DM + t] = acc;
}

// ---------------- out proj + residual --------------------------------------
__global__ __launch_bounds__(256) void k_projres(const float* __restrict__ ao,
                                                 const float* __restrict__ W,
                                                 const float* __restrict__ bias,
                                                 const float* __restrict__ xsr,
                                                 float* __restrict__ ysr) {
  __shared__ float sa[2][DM];
  int t = threadIdx.x, r0 = blockIdx.x * 2;
#pragma unroll
  for (int r = 0; r < 2; ++r) sa[r][t] = ao[(size_t)(r0 + r) * DM + t];
  __syncthreads();
  float a0 = 0.f, a1 = 0.f;
#pragma unroll 8
  for (int k = 0; k < DM; ++k) {
    float wv = W[k * DM + t];
    a0 += sa[0][k] * wv;
    a1 += sa[1][k] * wv;
  }
  float bb = bias[t];
  ysr[(size_t)r0 * DM + t] = xsr[(size_t)r0 * DM + t] + a0 + bb;
  ysr[(size_t)(r0 + 1) * DM + t] = xsr[(size_t)(r0 + 1) * DM + t] + a1 + bb;
}

// ---------------- feed-forward (exact GELU) + residual ---------------------
__global__ __launch_bounds__(256) void k_ffn(const float* __restrict__ ys,
                                             const float* __restrict__ W1,
                                             const float* __restrict__ b1,
                                             const float* __restrict__ W2,
                                             const float* __restrict__ b2,
                                             float* __restrict__ out) {
  __shared__ float sy[2][DM];
  __shared__ float sg[2][4 * DM];
  int t = threadIdx.x, r0 = blockIdx.x * 2;
#pragma unroll
  for (int r = 0; r < 2; ++r) sy[r][t] = ys[(size_t)(r0 + r) * DM + t];
  __syncthreads();
#pragma unroll
  for (int mc = 0; mc < 4; ++mc) {
    int m = mc * 256 + t;
    float a0 = b1[m], a1 = a0;
#pragma unroll 8
    for (int k = 0; k < DM; ++k) {
      float wv = W1[k * 1024 + m];
      a0 += sy[0][k] * wv;
      a1 += sy[1][k] * wv;
    }
    sg[0][m] = 0.5f * a0 * (1.0f + erff(a0 * 0.70710678118654752f));
    sg[1][m] = 0.5f * a1 * (1.0f + erff(a1 * 0.70710678118654752f));
  }
  __syncthreads();
  float z0 = b2[t] + sy[0][t], z1 = b2[t] + sy[1][t];
#pragma unroll 8
  for (int m = 0; m < 1024; ++m) {
    float wv = W2[m * 256 + t];
    z0 += sg[0][m] * wv;
    z1 += sg[1][m] * wv;
  }
  out[(size_t)r0 * DM + t] = z0;
  out[(size_t)(r0 + 1) * DM + t] = z1;
}

extern "C" void kernel_launch(void* const* d_in, const int* in_sizes, int n_in,
                              void* d_out, int out_size, void* d_ws, size_t ws_size,
                              hipStream_t stream) {
  const float* nodes = (const float*)d_in[0];
  const float* edges = (const float*)d_in[1];
  const float* W     = (const float*)d_in[2];
  const float* bias  = (const float*)d_in[3];
  const float* ln_g  = (const float*)d_in[4];
  const float* ln_b  = (const float*)d_in[5];
  const float* W1    = (const float*)d_in[6];
  const float* b1    = (const float*)d_in[7];
  const float* W2    = (const float*)d_in[8];
  const float* b2    = (const float*)d_in[9];
  float* out = (float*)d_out;

  char* ws = (char*)d_ws;
  float*  xs     = (float*)(ws + 0x000000);   // 512 KB  LN(nodes)
  float*  nqv    = (float*)(ws + 0x080000);   // 512 KB  node proj (q=k=v)
  half_t* WT16   = (half_t*)(ws + 0x100000);  // 128 KB  W^T f16
  float*  scores = (float*)(ws + 0x120000);   // 4 MB
  float*  ao     = (float*)(ws + 0x520000);   // 512 KB
  float*  ysr    = (float*)(ws + 0x5A0000);   // 512 KB
  float*  ys     = (float*)(ws + 0x620000);   // 512 KB

  k_ln<<<NB * NN, 256, 0, stream>>>(nodes, ln_g, ln_b, xs);
  k_wt16<<<DM, 256, 0, stream>>>(W, WT16);
  k_proj<<<NB * NN / 2, 256, 0, stream>>>(xs, W, bias, nqv);
  k_edge_scores<<<NB * NN * (NN / JT), 256, 0, stream>>>(edges, WT16, xs, bias, scores);
  k_smax_av<<<NB * NN, 256, 0, stream>>>(scores, nqv, ao);
  k_projres<<<NB * NN / 2, 256, 0, stream>>>(ao, W, bias, xs, ysr);
  k_ln<<<NB * NN, 256, 0, stream>>>(ysr, ln_g, ln_b, ys);
  k_ffn<<<NB * NN / 2, 256, 0, stream>>>(ys, W1, b1, W2, b2, out);
}

// Round 3
// 380.483 us; speedup vs baseline: 1.3098x; 1.3098x over previous
//
#include <hip/hip_runtime.h>

typedef _Float16 half_t;
typedef __attribute__((ext_vector_type(8))) _Float16 f16x8;
typedef __attribute__((ext_vector_type(4))) float f32x4;

#define DM 256
#define NH 8
#define HD 32
#define NN 256
#define NB 2
#define JT 32
#define KC 64

// ---------------- LayerNorm (one row per block, 256 threads) ----------------
__global__ __launch_bounds__(256) void k_ln(const float* __restrict__ in,
                                            const float* __restrict__ g,
                                            const float* __restrict__ be,
                                            float* __restrict__ out) {
  int row = blockIdx.x, t = threadIdx.x;
  float v = in[(size_t)row * DM + t];
  float s = v, q = v * v;
#pragma unroll
  for (int m = 1; m <= 32; m <<= 1) {
    s += __shfl_xor(s, m, 64);
    q += __shfl_xor(q, m, 64);
  }
  __shared__ float as_[4], aq_[4];
  int w = t >> 6, l = t & 63;
  if (l == 0) { as_[w] = s; aq_[w] = q; }
  __syncthreads();
  s = as_[0] + as_[1] + as_[2] + as_[3];
  q = aq_[0] + aq_[1] + aq_[2] + aq_[3];
  float mu = s * (1.0f / DM);
  float var = q * (1.0f / DM) - mu * mu;
  out[(size_t)row * DM + t] = (v - mu) * rsqrtf(var + 1e-5f) * g[t] + be[t];
}

// ---------------- W^T in f16 (MFMA A operand: WT[c,k] = W[k,c]) ------------
__global__ __launch_bounds__(256) void k_wt16(const float* __restrict__ W,
                                              half_t* __restrict__ WT) {
  int c = blockIdx.x, t = threadIdx.x;
  WT[c * DM + t] = (half_t)W[t * DM + c];
}

// ---------------- generic small GEMM: out = X[R x K] @ W[K x 256] + b (+res)
// 1024 threads, 8 rows/block, grid R/8. thread: col = t&255, row pair rg*2.
template <int K, bool RES>
__global__ __launch_bounds__(1024) void k_gemm(const float* __restrict__ X,
                                               const float* __restrict__ W,
                                               const float* __restrict__ bias,
                                               const float* __restrict__ res,
                                               float* __restrict__ out) {
  __shared__ float sx[8 * K];
  const int t = threadIdx.x;
  const int r0 = blockIdx.x * 8;
  for (int u = t; u < 2 * K; u += 1024) {
    int row = u / (K / 4), c4 = u % (K / 4);
    ((f32x4*)sx)[u] = *(const f32x4*)(X + (size_t)(r0 + row) * K + c4 * 4);
  }
  __syncthreads();
  const int col = t & 255;
  const int rg = t >> 8;
  const float* x0 = sx + (rg * 2) * K;
  const float* x1 = sx + (rg * 2 + 1) * K;
  float a0 = 0.f, a1 = 0.f;
#pragma unroll 8
  for (int k = 0; k < K; ++k) {
    float wv = W[(size_t)k * 256 + col];
    a0 += x0[k] * wv;
    a1 += x1[k] * wv;
  }
  float bb = bias[col];
  a0 += bb; a1 += bb;
  size_t o0 = (size_t)(r0 + rg * 2) * 256 + col;
  size_t o1 = o0 + 256;
  if (RES) { a0 += res[o0]; a1 += res[o1]; }
  out[o0] = a0;
  out[o1] = a1;
}

// ---------------- FF1: g = gelu(ys @ W1 + b1), 1024 cols ---------------------
__global__ __launch_bounds__(1024) void k_ffn1(const float* __restrict__ ys,
                                               const float* __restrict__ W1,
                                               const float* __restrict__ b1,
                                               float* __restrict__ g) {
  __shared__ float sx[8 * DM];
  const int t = threadIdx.x;
  const int r0 = blockIdx.x * 8;
  if (t < 512) {
    int row = t >> 6, c4 = t & 63;
    ((f32x4*)sx)[t] = *(const f32x4*)(ys + (size_t)(r0 + row) * DM + c4 * 4);
  }
  __syncthreads();
  float acc[8];
  float bb = b1[t];
#pragma unroll
  for (int r = 0; r < 8; ++r) acc[r] = bb;
#pragma unroll 8
  for (int k = 0; k < DM; ++k) {
    float wv = W1[(size_t)k * 1024 + t];
#pragma unroll
    for (int r = 0; r < 8; ++r) acc[r] += sx[r * DM + k] * wv;
  }
#pragma unroll
  for (int r = 0; r < 8; ++r) {
    float v = acc[r];
    g[(size_t)(r0 + r) * 1024 + t] = 0.5f * v * (1.0f + erff(v * 0.70710678118654752f));
  }
}

// ---------------- fused edge proj + scores ---------------------------------
// Q~[j,:] = (edge[j]+x_i)@W + 2b ; K~[j,:] = (edge[j]+x_j)@W + 2b
// score[h,j] = (1/sqrt32) * sum_{c in h} Q~ K~ ; out = 10*tanh(.)
__global__ __launch_bounds__(256, 3) void k_edge_scores(
    const float* __restrict__ edges, const half_t* __restrict__ WT,
    const float* __restrict__ xs, const float* __restrict__ bias,
    float* __restrict__ scores) {
  __shared__ __align__(16) char smem[40960];
  const int tid = threadIdx.x;
  const int l = tid & 63;
  const int w = tid >> 6;
  const int idx = blockIdx.x;
  const int jb = idx & 7;
  const int i = (idx >> 3) & (NN - 1);
  const int b = idx >> 11;
  const int j0 = jb * JT;

  f32x4 accq[4][2], acck[4][2];
#pragma unroll
  for (int ct = 0; ct < 4; ++ct) {
    f32x4 bv = *(const f32x4*)(bias + w * 64 + ct * 16 + (l >> 4) * 4);
    f32x4 iv = {2.f * bv[0], 2.f * bv[1], 2.f * bv[2], 2.f * bv[3]};
#pragma unroll
    for (int jt = 0; jt < 2; ++jt) { accq[ct][jt] = iv; acck[ct][jt] = iv; }
  }

  const float* eg = edges + ((size_t)(b * NN + i) * NN + j0) * DM;
  const float* xb = xs + (size_t)b * NN * DM;
  const float* xi = xb + (size_t)i * DM;
  const int f4 = tid & 15, row0 = tid >> 4;

  // prefetch chunk 0 (edge + x_j + x_i) into registers
  f32x4 pe[2], pxj[2], pxi;
#pragma unroll
  for (int q = 0; q < 2; ++q) {
    int row = row0 + q * 16;
    pe[q] = *(const f32x4*)(eg + row * DM + f4 * 4);
    pxj[q] = *(const f32x4*)(xb + (size_t)(j0 + row) * DM + f4 * 4);
  }
  pxi = *(const f32x4*)(xi + f4 * 4);

  for (int kc = 0; kc < 4; ++kc) {
    // WT chunk -> LDS direct (linear dest, inverse-swizzled global source)
    {
      const char* wtb = (const char*)WT;
#pragma unroll
      for (int q = 0; q < 8; ++q) {
        int ub = (w * 8 + q) * 64;
        int cc = (ub + l) >> 3;
        int ss = l & 7;
        const void* src = wtb + cc * 512 + kc * 128 + ((ss ^ (cc & 7)) * 16);
        __builtin_amdgcn_global_load_lds(
            (const __attribute__((address_space(1))) unsigned int*)src,
            (__attribute__((address_space(3))) unsigned int*)(smem + 8192 + ub * 16),
            16, 0, 0);
      }
    }
    // convert + swizzled write of A1 (edge+x_i) and A2 (edge+x_j)
#pragma unroll
    for (int q = 0; q < 2; ++q) {
      int row = row0 + q * 16;
      union { unsigned long long u; half_t h[4]; } a1, a2;
#pragma unroll
      for (int z = 0; z < 4; ++z) {
        a1.h[z] = (half_t)(pe[q][z] + pxi[z]);
        a2.h[z] = (half_t)(pe[q][z] + pxj[q][z]);
      }
      int off = (row * 128 + f4 * 8) ^ ((row & 7) << 4);
      *(unsigned long long*)(smem + off) = a1.u;
      *(unsigned long long*)(smem + 4096 + off) = a2.u;
    }
    __syncthreads();  // drains vmcnt (WT in LDS) + lgkm (A writes)
    // prefetch next chunk -- overlaps the MFMA phase below
    if (kc < 3) {
#pragma unroll
      for (int q = 0; q < 2; ++q) {
        int row = row0 + q * 16;
        pe[q] = *(const f32x4*)(eg + row * DM + (kc + 1) * KC + f4 * 4);
        pxj[q] = *(const f32x4*)(xb + (size_t)(j0 + row) * DM + (kc + 1) * KC + f4 * 4);
      }
      pxi = *(const f32x4*)(xi + (kc + 1) * KC + f4 * 4);
    }
#pragma unroll
    for (int ks = 0; ks < 2; ++ks) {
      f16x8 fq[2], fk[2];
#pragma unroll
      for (int jt = 0; jt < 2; ++jt) {
        int r = jt * 16 + (l & 15);
        int off = (r * 128 + ks * 64 + ((l >> 4) * 16)) ^ ((r & 7) << 4);
        fq[jt] = *(const f16x8*)(smem + off);
        fk[jt] = *(const f16x8*)(smem + 4096 + off);
      }
#pragma unroll
      for (int ct = 0; ct < 4; ++ct) {
        int c = w * 64 + ct * 16 + (l & 15);
        int off = (c * 128 + ks * 64 + ((l >> 4) * 16)) ^ ((c & 7) << 4);
        f16x8 wf = *(const f16x8*)(smem + 8192 + off);
#pragma unroll
        for (int jt = 0; jt < 2; ++jt) {
          accq[ct][jt] = __builtin_amdgcn_mfma_f32_16x16x32_f16(wf, fq[jt], accq[ct][jt], 0, 0, 0);
          acck[ct][jt] = __builtin_amdgcn_mfma_f32_16x16x32_f16(wf, fk[jt], acck[ct][jt], 0, 0, 0);
        }
      }
    }
    __syncthreads();
  }

  const float scale = 0.17677669529663687f;  // 1/sqrt(32)
#pragma unroll
  for (int a = 0; a < 2; ++a) {
#pragma unroll
    for (int jt = 0; jt < 2; ++jt) {
      float s = 0.f;
#pragma unroll
      for (int u = 0; u < 2; ++u) {
        int ct = a * 2 + u;
#pragma unroll
        for (int rr = 0; rr < 4; ++rr) s += accq[ct][jt][rr] * acck[ct][jt][rr];
      }
      s += __shfl_xor(s, 16, 64);
      s += __shfl_xor(s, 32, 64);
      float sc = 10.0f * tanhf(s * scale);
      if (l < 16) {
        int h = w * 2 + a;
        int jg = j0 + jt * 16 + l;
        scores[(((size_t)(b * NH) + h) * NN + i) * NN + jg] = sc;
      }
    }
  }
}

// ---------------- fused softmax + attn@V, 1024 threads, j split 4-way ------
__global__ __launch_bounds__(1024) void k_smax_av(const float* __restrict__ scores,
                                                  const float* __restrict__ nqv,
                                                  float* __restrict__ ao) {
  __shared__ float sp[NH * NN];
  __shared__ float pp[4 * 256];
  const int t = threadIdx.x;
  const int b = blockIdx.x >> 8, i = blockIdx.x & 255;
#pragma unroll
  for (int p = 0; p < 2; ++p) {
    int idx = p * 1024 + t;
    sp[idx] = scores[(((size_t)(b * NH) + (idx >> 8)) * NN + i) * NN + (idx & 255)];
  }
  __syncthreads();
  const int w = t >> 6, l = t & 63;
  if (w < 8) {
    f32x4 v = *(f32x4*)(sp + w * NN + l * 4);
    float m = fmaxf(fmaxf(v[0], v[1]), fmaxf(v[2], v[3]));
#pragma unroll
    for (int mm = 1; mm <= 32; mm <<= 1) m = fmaxf(m, __shfl_xor(m, mm, 64));
    v[0] = __expf(v[0] - m); v[1] = __expf(v[1] - m);
    v[2] = __expf(v[2] - m); v[3] = __expf(v[3] - m);
    float s = v[0] + v[1] + v[2] + v[3];
#pragma unroll
    for (int mm = 1; mm <= 32; mm <<= 1) s += __shfl_xor(s, mm, 64);
    float inv = 1.0f / s;
    v[0] *= inv; v[1] *= inv; v[2] *= inv; v[3] *= inv;
    *(f32x4*)(sp + w * NN + l * 4) = v;
  }
  __syncthreads();
  const int d = t & 255, jg = t >> 8, h = d >> 5;
  const float* vb = nqv + (size_t)b * NN * DM;
  float acc = 0.f;
#pragma unroll 8
  for (int jj = 0; jj < 64; ++jj) {
    int j = jg * 64 + jj;
    acc += sp[h * 256 + j] * vb[(size_t)j * DM + d];
  }
  pp[jg * 256 + d] = acc;
  __syncthreads();
  if (t < 256)
    ao[((size_t)(b * NN) + i) * DM + t] = pp[t] + pp[256 + t] + pp[512 + t] + pp[768 + t];
}

extern "C" void kernel_launch(void* const* d_in, const int* in_sizes, int n_in,
                              void* d_out, int out_size, void* d_ws, size_t ws_size,
                              hipStream_t stream) {
  const float* nodes = (const float*)d_in[0];
  const float* edges = (const float*)d_in[1];
  const float* W     = (const float*)d_in[2];
  const float* bias  = (const float*)d_in[3];
  const float* ln_g  = (const float*)d_in[4];
  const float* ln_b  = (const float*)d_in[5];
  const float* W1    = (const float*)d_in[6];
  const float* b1    = (const float*)d_in[7];
  const float* W2    = (const float*)d_in[8];
  const float* b2    = (const float*)d_in[9];
  float* out = (float*)d_out;

  char* ws = (char*)d_ws;
  float*  xs     = (float*)(ws + 0x000000);   // 512 KB  LN(nodes)
  float*  nqv    = (float*)(ws + 0x080000);   // 512 KB  node proj (q=k=v)
  half_t* WT16   = (half_t*)(ws + 0x100000);  // 128 KB  W^T f16
  float*  scores = (float*)(ws + 0x120000);   // 4 MB
  float*  g      = (float*)(ws + 0x120000);   // 2 MB (reuses scores, dead by then)
  float*  ao     = (float*)(ws + 0x520000);   // 512 KB
  float*  ysr    = (float*)(ws + 0x5A0000);   // 512 KB
  float*  ys     = (float*)(ws + 0x620000);   // 512 KB

  k_ln<<<NB * NN, 256, 0, stream>>>(nodes, ln_g, ln_b, xs);
  k_wt16<<<DM, 256, 0, stream>>>(W, WT16);
  k_gemm<256, false><<<NB * NN / 8, 1024, 0, stream>>>(xs, W, bias, nullptr, nqv);
  k_edge_scores<<<NB * NN * (NN / JT), 256, 0, stream>>>(edges, WT16, xs, bias, scores);
  k_smax_av<<<NB * NN, 1024, 0, stream>>>(scores, nqv, ao);
  k_gemm<256, true><<<NB * NN / 8, 1024, 0, stream>>>(ao, W, bias, xs, ysr);
  k_ln<<<NB * NN, 256, 0, stream>>>(ysr, ln_g, ln_b, ys);
  k_ffn1<<<NB * NN / 8, 1024, 0, stream>>>(ys, W1, b1, g);
  k_gemm<1024, true><<<NB * NN / 8, 1024, 0, stream>>>(g, W2, b2, ys, out);
}

// Round 4
// 319.171 us; speedup vs baseline: 1.5614x; 1.1921x over previous
//
#include <hip/hip_runtime.h>

typedef _Float16 half_t;
typedef __attribute__((ext_vector_type(8))) _Float16 f16x8;
typedef __attribute__((ext_vector_type(4))) float f32x4;

#define DM 256
#define NH 8
#define NN 256
#define NB 2
#define JT 32
#define KC 64

// ---- fused LN + node proj: xs = LN(nodes); nqv = xs@W + b ------------------
__global__ __launch_bounds__(1024) void k_ln_proj(
    const float* __restrict__ nodes, const float* __restrict__ W,
    const float* __restrict__ bias, const float* __restrict__ ln_g,
    const float* __restrict__ ln_b, float* __restrict__ xs,
    float* __restrict__ nqv) {
  __shared__ float sx[2][DM];
  __shared__ float pp[4][2][DM];
  __shared__ float rs[8], rq[8];
  const int t = threadIdx.x;
  const int r0 = blockIdx.x * 2;
  const int row = t >> 8, col = t & 255;
  float v = 0.f;
  if (t < 512) v = nodes[(size_t)(r0 + row) * DM + col];
  float s = v, q = v * v;
#pragma unroll
  for (int m = 1; m <= 32; m <<= 1) {
    s += __shfl_xor(s, m, 64);
    q += __shfl_xor(q, m, 64);
  }
  if (t < 512 && (t & 63) == 0) { rs[t >> 6] = s; rq[t >> 6] = q; }
  __syncthreads();
  if (t < 512) {
    int rb = row * 4;
    float ss = rs[rb] + rs[rb + 1] + rs[rb + 2] + rs[rb + 3];
    float qq = rq[rb] + rq[rb + 1] + rq[rb + 2] + rq[rb + 3];
    float mu = ss * (1.f / DM);
    float var = qq * (1.f / DM) - mu * mu;
    float xv = (v - mu) * rsqrtf(var + 1e-5f) * ln_g[col] + ln_b[col];
    sx[row][col] = xv;
    xs[(size_t)(r0 + row) * DM + col] = xv;
  }
  __syncthreads();
  const int rg = t >> 8;
  float a0 = 0.f, a1 = 0.f;
#pragma unroll 8
  for (int kk = 0; kk < 64; ++kk) {
    int k = rg * 64 + kk;
    float wv = W[(size_t)k * DM + col];
    a0 += sx[0][k] * wv;
    a1 += sx[1][k] * wv;
  }
  pp[rg][0][col] = a0;
  pp[rg][1][col] = a1;
  __syncthreads();
  if (t < 512) {
    float r = pp[0][row][col] + pp[1][row][col] + pp[2][row][col] +
              pp[3][row][col] + bias[col];
    nqv[(size_t)(r0 + row) * DM + col] = r;
  }
}

// ---------------- W^T in f16 (WT[c,k] = W[k,c]) ----------------------------
__global__ __launch_bounds__(256) void k_wt16(const float* __restrict__ W,
                                              half_t* __restrict__ WT) {
  int c = blockIdx.x, t = threadIdx.x;
  WT[c * DM + t] = (half_t)W[t * DM + c];
}

// ---------------- fused edge proj + scores ---------------------------------
// Q~[j,:] = (edge[j]+x_i)@W + 2b ; K~[j,:] = (edge[j]+x_j)@W + 2b
// score[h,j] = 10*tanh( (1/sqrt32) * sum_{c in h} Q~ K~ )
// A tiles (j x k) staged via LDS (swizzled); WT fragments straight from L2.
__global__ __launch_bounds__(256, 3) void k_edge_scores(
    const float* __restrict__ edges, const half_t* __restrict__ WT,
    const float* __restrict__ xs, const float* __restrict__ bias,
    float* __restrict__ scores) {
  __shared__ __align__(16) char smem[8192];
  const int tid = threadIdx.x;
  const int l = tid & 63;
  const int w = tid >> 6;
  const int idx = blockIdx.x;
  const int jb = idx & 7;
  const int i = (idx >> 3) & (NN - 1);
  const int b = idx >> 11;
  const int j0 = jb * JT;

  f32x4 accq[4][2], acck[4][2];
#pragma unroll
  for (int ct = 0; ct < 4; ++ct) {
    f32x4 bv = *(const f32x4*)(bias + w * 64 + ct * 16 + (l >> 4) * 4);
    f32x4 iv = {2.f * bv[0], 2.f * bv[1], 2.f * bv[2], 2.f * bv[3]};
#pragma unroll
    for (int jt = 0; jt < 2; ++jt) { accq[ct][jt] = iv; acck[ct][jt] = iv; }
  }

  const float* eg = edges + ((size_t)(b * NN + i) * NN + j0) * DM;
  const float* xb = xs + (size_t)b * NN * DM;
  const float* xi = xb + (size_t)i * DM;
  const int f4 = tid & 15, row0 = tid >> 4;
  const char* wtb = (const char*)WT;

  // prefetch chunk 0
  f32x4 pe[2], pxj[2], pxi;
#pragma unroll
  for (int q = 0; q < 2; ++q) {
    int row = row0 + q * 16;
    pe[q] = *(const f32x4*)(eg + row * DM + f4 * 4);
    pxj[q] = *(const f32x4*)(xb + (size_t)(j0 + row) * DM + f4 * 4);
  }
  pxi = *(const f32x4*)(xi + f4 * 4);

  for (int kc = 0; kc < 4; ++kc) {
    // WT fragments for this chunk: straight from global (L2-hot)
    f16x8 wf[2][4];
#pragma unroll
    for (int ks = 0; ks < 2; ++ks)
#pragma unroll
      for (int ct = 0; ct < 4; ++ct) {
        int c = w * 64 + ct * 16 + (l & 15);
        wf[ks][ct] = *(const f16x8*)(wtb + c * 512 + kc * 128 + ks * 64 +
                                     ((l >> 4) * 16));
      }
    // convert + swizzled LDS write of A1 (edge+x_i) and A2 (edge+x_j)
#pragma unroll
    for (int q = 0; q < 2; ++q) {
      int row = row0 + q * 16;
      union { unsigned long long u; half_t h[4]; } a1, a2;
#pragma unroll
      for (int z = 0; z < 4; ++z) {
        a1.h[z] = (half_t)(pe[q][z] + pxi[z]);
        a2.h[z] = (half_t)(pe[q][z] + pxj[q][z]);
      }
      int off = (row * 128 + f4 * 8) ^ ((row & 7) << 4);
      *(unsigned long long*)(smem + off) = a1.u;
      *(unsigned long long*)(smem + 4096 + off) = a2.u;
    }
    __syncthreads();
    // prefetch next chunk (overlaps MFMA phase)
    if (kc < 3) {
#pragma unroll
      for (int q = 0; q < 2; ++q) {
        int row = row0 + q * 16;
        pe[q] = *(const f32x4*)(eg + row * DM + (kc + 1) * KC + f4 * 4);
        pxj[q] = *(const f32x4*)(xb + (size_t)(j0 + row) * DM + (kc + 1) * KC + f4 * 4);
      }
      pxi = *(const f32x4*)(xi + (kc + 1) * KC + f4 * 4);
    }
#pragma unroll
    for (int ks = 0; ks < 2; ++ks) {
      f16x8 fq[2], fk[2];
#pragma unroll
      for (int jt = 0; jt < 2; ++jt) {
        int r = jt * 16 + (l & 15);
        int off = (r * 128 + ks * 64 + ((l >> 4) * 16)) ^ ((r & 7) << 4);
        fq[jt] = *(const f16x8*)(smem + off);
        fk[jt] = *(const f16x8*)(smem + 4096 + off);
      }
#pragma unroll
      for (int ct = 0; ct < 4; ++ct)
#pragma unroll
        for (int jt = 0; jt < 2; ++jt) {
          accq[ct][jt] = __builtin_amdgcn_mfma_f32_16x16x32_f16(wf[ks][ct], fq[jt], accq[ct][jt], 0, 0, 0);
          acck[ct][jt] = __builtin_amdgcn_mfma_f32_16x16x32_f16(wf[ks][ct], fk[jt], acck[ct][jt], 0, 0, 0);
        }
    }
    __syncthreads();
  }

  const float scale = 0.17677669529663687f;  // 1/sqrt(32)
#pragma unroll
  for (int a = 0; a < 2; ++a) {
#pragma unroll
    for (int jt = 0; jt < 2; ++jt) {
      float s = 0.f;
#pragma unroll
      for (int u = 0; u < 2; ++u) {
        int ct = a * 2 + u;
#pragma unroll
        for (int rr = 0; rr < 4; ++rr) s += accq[ct][jt][rr] * acck[ct][jt][rr];
      }
      s += __shfl_xor(s, 16, 64);
      s += __shfl_xor(s, 32, 64);
      float sc = 10.0f * tanhf(s * scale);
      if (l < 16) {
        int h = w * 2 + a;
        int jg = j0 + jt * 16 + l;
        scores[(((size_t)(b * NH) + h) * NN + i) * NN + jg] = sc;
      }
    }
  }
}

// ---------------- fused softmax + attn@V, 1024 threads, j split 4-way ------
__global__ __launch_bounds__(1024) void k_smax_av(const float* __restrict__ scores,
                                                  const float* __restrict__ nqv,
                                                  float* __restrict__ ao) {
  __shared__ float sp[NH * NN];
  __shared__ float pp[4 * 256];
  const int t = threadIdx.x;
  const int b = blockIdx.x >> 8, i = blockIdx.x & 255;
#pragma unroll
  for (int p = 0; p < 2; ++p) {
    int idx = p * 1024 + t;
    sp[idx] = scores[(((size_t)(b * NH) + (idx >> 8)) * NN + i) * NN + (idx & 255)];
  }
  __syncthreads();
  const int w = t >> 6, l = t & 63;
  if (w < 8) {
    f32x4 v = *(f32x4*)(sp + w * NN + l * 4);
    float m = fmaxf(fmaxf(v[0], v[1]), fmaxf(v[2], v[3]));
#pragma unroll
    for (int mm = 1; mm <= 32; mm <<= 1) m = fmaxf(m, __shfl_xor(m, mm, 64));
    v[0] = __expf(v[0] - m); v[1] = __expf(v[1] - m);
    v[2] = __expf(v[2] - m); v[3] = __expf(v[3] - m);
    float s = v[0] + v[1] + v[2] + v[3];
#pragma unroll
    for (int mm = 1; mm <= 32; mm <<= 1) s += __shfl_xor(s, mm, 64);
    float inv = 1.0f / s;
    v[0] *= inv; v[1] *= inv; v[2] *= inv; v[3] *= inv;
    *(f32x4*)(sp + w * NN + l * 4) = v;
  }
  __syncthreads();
  const int d = t & 255, jg = t >> 8, h = d >> 5;
  const float* vb = nqv + (size_t)b * NN * DM;
  float acc = 0.f;
#pragma unroll 8
  for (int jj = 0; jj < 64; ++jj) {
    int j = jg * 64 + jj;
    acc += sp[h * 256 + j] * vb[(size_t)j * DM + d];
  }
  pp[jg * 256 + d] = acc;
  __syncthreads();
  if (t < 256)
    ao[((size_t)(b * NN) + i) * DM + t] = pp[t] + pp[256 + t] + pp[512 + t] + pp[768 + t];
}

// ---- fused out-proj + residual + LN: ys = LN(xs + ao@W + b) ---------------
__global__ __launch_bounds__(1024) void k_gemm_res_ln(
    const float* __restrict__ ao, const float* __restrict__ W,
    const float* __restrict__ bias, const float* __restrict__ xs,
    const float* __restrict__ ln_g, const float* __restrict__ ln_b,
    float* __restrict__ ys) {
  __shared__ float sa[2][DM];
  __shared__ float pp[4][2][DM];
  __shared__ float rs[8], rq[8];
  const int t = threadIdx.x;
  const int r0 = blockIdx.x * 2;
  const int row = t >> 8, col = t & 255;
  if (t < 512) sa[row][col] = ao[(size_t)(r0 + row) * DM + col];
  __syncthreads();
  const int rg = t >> 8;
  float a0 = 0.f, a1 = 0.f;
#pragma unroll 8
  for (int kk = 0; kk < 64; ++kk) {
    int k = rg * 64 + kk;
    float wv = W[(size_t)k * DM + col];
    a0 += sa[0][k] * wv;
    a1 += sa[1][k] * wv;
  }
  pp[rg][0][col] = a0;
  pp[rg][1][col] = a1;
  __syncthreads();
  float val = 0.f;
  if (t < 512) {
    val = pp[0][row][col] + pp[1][row][col] + pp[2][row][col] +
          pp[3][row][col] + bias[col] + xs[(size_t)(r0 + row) * DM + col];
  }
  float s = val, q = val * val;
#pragma unroll
  for (int m = 1; m <= 32; m <<= 1) {
    s += __shfl_xor(s, m, 64);
    q += __shfl_xor(q, m, 64);
  }
  if (t < 512 && (t & 63) == 0) { rs[t >> 6] = s; rq[t >> 6] = q; }
  __syncthreads();
  if (t < 512) {
    int rb = row * 4;
    float ss = rs[rb] + rs[rb + 1] + rs[rb + 2] + rs[rb + 3];
    float qq = rq[rb] + rq[rb + 1] + rq[rb + 2] + rq[rb + 3];
    float mu = ss * (1.f / DM);
    float var = qq * (1.f / DM) - mu * mu;
    ys[(size_t)(r0 + row) * DM + col] =
        (val - mu) * rsqrtf(var + 1e-5f) * ln_g[col] + ln_b[col];
  }
}

// ---------------- FF1: g = gelu(ys @ W1 + b1) ------------------------------
__global__ __launch_bounds__(1024) void k_ffn1(const float* __restrict__ ys,
                                               const float* __restrict__ W1,
                                               const float* __restrict__ b1,
                                               float* __restrict__ g) {
  __shared__ float sy[2][DM];
  const int t = threadIdx.x;
  const int r0 = blockIdx.x * 2;
  if (t < 512) sy[t >> 8][t & 255] = ys[(size_t)(r0 + (t >> 8)) * DM + (t & 255)];
  __syncthreads();
  float a0 = b1[t], a1 = a0;
#pragma unroll 8
  for (int k = 0; k < DM; ++k) {
    float wv = W1[(size_t)k * 1024 + t];
    a0 += sy[0][k] * wv;
    a1 += sy[1][k] * wv;
  }
  g[(size_t)r0 * 1024 + t] = 0.5f * a0 * (1.0f + erff(a0 * 0.70710678118654752f));
  g[(size_t)(r0 + 1) * 1024 + t] = 0.5f * a1 * (1.0f + erff(a1 * 0.70710678118654752f));
}

// ---------------- FF2 + residual: out = g @ W2 + b2 + ys -------------------
__global__ __launch_bounds__(1024) void k_ffn2(const float* __restrict__ g,
                                               const float* __restrict__ W2,
                                               const float* __restrict__ b2,
                                               const float* __restrict__ ys,
                                               float* __restrict__ out) {
  __shared__ float sg[2][1024];
  __shared__ float pp[4][2][256];
  const int t = threadIdx.x;
  const int r0 = blockIdx.x * 2;
  if (t < 512) ((f32x4*)sg)[t] = *(const f32x4*)(g + (size_t)r0 * 1024 + t * 4);
  __syncthreads();
  const int kg = t >> 8, col = t & 255;
  float a0 = 0.f, a1 = 0.f;
#pragma unroll 8
  for (int kk = 0; kk < 256; ++kk) {
    int k = kg * 256 + kk;
    float wv = W2[(size_t)k * 256 + col];
    a0 += sg[0][k] * wv;
    a1 += sg[1][k] * wv;
  }
  pp[kg][0][col] = a0;
  pp[kg][1][col] = a1;
  __syncthreads();
  if (t < 512) {
    int row = t >> 8;
    float r = pp[0][row][col] + pp[1][row][col] + pp[2][row][col] +
              pp[3][row][col] + b2[col] + ys[(size_t)(r0 + row) * DM + col];
    out[(size_t)(r0 + row) * DM + col] = r;
  }
}

extern "C" void kernel_launch(void* const* d_in, const int* in_sizes, int n_in,
                              void* d_out, int out_size, void* d_ws, size_t ws_size,
                              hipStream_t stream) {
  const float* nodes = (const float*)d_in[0];
  const float* edges = (const float*)d_in[1];
  const float* W     = (const float*)d_in[2];
  const float* bias  = (const float*)d_in[3];
  const float* ln_g  = (const float*)d_in[4];
  const float* ln_b  = (const float*)d_in[5];
  const float* W1    = (const float*)d_in[6];
  const float* b1    = (const float*)d_in[7];
  const float* W2    = (const float*)d_in[8];
  const float* b2    = (const float*)d_in[9];
  float* out = (float*)d_out;

  char* ws = (char*)d_ws;
  float*  xs     = (float*)(ws + 0x000000);   // 512 KB
  float*  nqv    = (float*)(ws + 0x080000);   // 512 KB
  half_t* WT16   = (half_t*)(ws + 0x100000);  // 128 KB
  float*  scores = (float*)(ws + 0x120000);   // 4 MB
  float*  g      = (float*)(ws + 0x120000);   // 2 MB (reuses scores)
  float*  ao     = (float*)(ws + 0x520000);   // 512 KB
  float*  ys     = (float*)(ws + 0x5A0000);   // 512 KB

  k_ln_proj<<<NB * NN / 2, 1024, 0, stream>>>(nodes, W, bias, ln_g, ln_b, xs, nqv);
  k_wt16<<<DM, 256, 0, stream>>>(W, WT16);
  k_edge_scores<<<NB * NN * (NN / JT), 256, 0, stream>>>(edges, WT16, xs, bias, scores);
  k_smax_av<<<NB * NN, 1024, 0, stream>>>(scores, nqv, ao);
  k_gemm_res_ln<<<NB * NN / 2, 1024, 0, stream>>>(ao, W, bias, xs, ln_g, ln_b, ys);
  k_ffn1<<<NB * NN / 2, 1024, 0, stream>>>(ys, W1, b1, g);
  k_ffn2<<<NB * NN / 2, 1024, 0, stream>>>(g, W2, b2, ys, out);
}

// Round 7
// 309.292 us; speedup vs baseline: 1.6113x; 1.0319x over previous
//
#include <hip/hip_runtime.h>

typedef _Float16 half_t;
typedef __attribute__((ext_vector_type(8))) _Float16 f16x8;
typedef __attribute__((ext_vector_type(4))) float f32x4;

#define DM 256
#define NH 8
#define NN 256
#define NB 2
#define JT 32

// ---- fused LN + node proj: xs = LN(nodes); nqv = xs@W + b; nqvpb = nqv + b -
__global__ __launch_bounds__(1024) void k_ln_proj(
    const float* __restrict__ nodes, const float* __restrict__ W,
    const float* __restrict__ bias, const float* __restrict__ ln_g,
    const float* __restrict__ ln_b, float* __restrict__ xs,
    float* __restrict__ nqv, float* __restrict__ nqvpb) {
  __shared__ float sx[2][DM];
  __shared__ float pp[4][2][DM];
  __shared__ float rs[8], rq[8];
  const int t = threadIdx.x;
  const int r0 = blockIdx.x * 2;
  const int row = t >> 8, col = t & 255;
  float v = 0.f;
  if (t < 512) v = nodes[(size_t)(r0 + row) * DM + col];
  float s = v, q = v * v;
#pragma unroll
  for (int m = 1; m <= 32; m <<= 1) {
    s += __shfl_xor(s, m, 64);
    q += __shfl_xor(q, m, 64);
  }
  if (t < 512 && (t & 63) == 0) { rs[t >> 6] = s; rq[t >> 6] = q; }
  __syncthreads();
  if (t < 512) {
    int rb = row * 4;
    float ss = rs[rb] + rs[rb + 1] + rs[rb + 2] + rs[rb + 3];
    float qq = rq[rb] + rq[rb + 1] + rq[rb + 2] + rq[rb + 3];
    float mu = ss * (1.f / DM);
    float var = qq * (1.f / DM) - mu * mu;
    float xv = (v - mu) * rsqrtf(var + 1e-5f) * ln_g[col] + ln_b[col];
    sx[row][col] = xv;
    xs[(size_t)(r0 + row) * DM + col] = xv;
  }
  __syncthreads();
  const int rg = t >> 8;
  float a0 = 0.f, a1 = 0.f;
#pragma unroll 8
  for (int kk = 0; kk < 64; ++kk) {
    int k = rg * 64 + kk;
    float wv = W[(size_t)k * DM + col];
    a0 += sx[0][k] * wv;
    a1 += sx[1][k] * wv;
  }
  pp[rg][0][col] = a0;
  pp[rg][1][col] = a1;
  __syncthreads();
  if (t < 512) {
    float bb = bias[col];
    float r = pp[0][row][col] + pp[1][row][col] + pp[2][row][col] +
              pp[3][row][col] + bb;
    nqv[(size_t)(r0 + row) * DM + col] = r;
    nqvpb[(size_t)(r0 + row) * DM + col] = r + bb;
  }
}

// ---------------- W^T in f16 (WT[c,k] = W[k,c]) ----------------------------
__global__ __launch_bounds__(256) void k_wt16(const float* __restrict__ W,
                                              half_t* __restrict__ WT) {
  int c = blockIdx.x, t = threadIdx.x;
  WT[c * DM + t] = (half_t)W[t * DM + c];
}

// ---------------- fused edge proj + scores ---------------------------------
// EP = edge[b,i,j0:j0+32,:] @ W (f16 MFMA, f32 accum, swapped: D[c,j])
// score[h,j] = 10*tanh( (1/sqrt32) * sum_{c in h} (EP+qi_c)(EP+kj_c) )
// qi = nqvpb[b,i,:], kj = nqvpb[b,j,:]  (f32, staged in LDS)
__global__ __launch_bounds__(256, 4) void k_edge_scores(
    const float* __restrict__ edges, const half_t* __restrict__ WT,
    const float* __restrict__ nqvpb, float* __restrict__ scores) {
  __shared__ __align__(16) char smem[4096 + 32 * 1040];
  const int tid = threadIdx.x;
  const int l = tid & 63;
  const int w = tid >> 6;
  const int idx = blockIdx.x;
  const int jb = idx & 7;
  const int i = (idx >> 3) & (NN - 1);
  const int b = idx >> 11;
  const int j0 = jb * JT;

  float* nlds = (float*)(smem + 4096);  // 32 rows, stride 260 floats (padded)

  // stage nqvpb[b, j0..j0+31, :] -> LDS f32
  const float* nb_ = nqvpb + ((size_t)(b * NN) + j0) * DM;
#pragma unroll
  for (int p = 0; p < 8; ++p) {
    int u = p * 256 + tid;  // 2048 f32x4 units
    int row = u >> 6, c4 = u & 63;
    f32x4 v = *(const f32x4*)(nb_ + (size_t)row * DM + c4 * 4);
    *(f32x4*)(nlds + row * 260 + c4 * 4) = v;
  }

  f32x4 acc[4][2];
#pragma unroll
  for (int ct = 0; ct < 4; ++ct)
#pragma unroll
    for (int jt = 0; jt < 2; ++jt) acc[ct][jt] = (f32x4){0.f, 0.f, 0.f, 0.f};

  const float* eg = edges + ((size_t)(b * NN + i) * NN + j0) * DM;
  const int f4 = tid & 15, row0 = tid >> 4;
  const char* wtb = (const char*)WT;

  // prefetch edge chunk 0
  f32x4 pe[2];
  pe[0] = *(const f32x4*)(eg + row0 * DM + f4 * 4);
  pe[1] = *(const f32x4*)(eg + (row0 + 16) * DM + f4 * 4);

  for (int kc = 0; kc < 4; ++kc) {
    // issue WT fragment loads early (L2-hot); latency hides under convert+barrier
    f16x8 wf[2][4];
#pragma unroll
    for (int ks = 0; ks < 2; ++ks)
#pragma unroll
      for (int ct = 0; ct < 4; ++ct) {
        int c = w * 64 + ct * 16 + (l & 15);
        wf[ks][ct] = *(const f16x8*)(wtb + c * 512 + kc * 128 + ks * 64 +
                                     ((l >> 4) * 16));
      }
    // convert + swizzled LDS write of A (edge tile)
#pragma unroll
    for (int q = 0; q < 2; ++q) {
      int row = row0 + q * 16;
      union { unsigned long long u; half_t h[4]; } a1;
#pragma unroll
      for (int z = 0; z < 4; ++z) a1.h[z] = (half_t)pe[q][z];
      int off = (row * 128 + f4 * 8) ^ ((row & 7) << 4);
      *(unsigned long long*)(smem + off) = a1.u;
    }
    __syncthreads();
    // prefetch next edge chunk (overlaps MFMA)
    if (kc < 3) {
      pe[0] = *(const f32x4*)(eg + row0 * DM + (kc + 1) * 64 + f4 * 4);
      pe[1] = *(const f32x4*)(eg + (row0 + 16) * DM + (kc + 1) * 64 + f4 * 4);
    }
#pragma unroll
    for (int ks = 0; ks < 2; ++ks) {
      f16x8 fq[2];
#pragma unroll
      for (int jt = 0; jt < 2; ++jt) {
        int r = jt * 16 + (l & 15);
        int off = (r * 128 + ks * 64 + ((l >> 4) * 16)) ^ ((r & 7) << 4);
        fq[jt] = *(const f16x8*)(smem + off);
      }
#pragma unroll
      for (int ct = 0; ct < 4; ++ct)
#pragma unroll
        for (int jt = 0; jt < 2; ++jt)
          acc[ct][jt] = __builtin_amdgcn_mfma_f32_16x16x32_f16(
              wf[ks][ct], fq[jt], acc[ct][jt], 0, 0, 0);
    }
    __syncthreads();
  }

  // epilogue: score = sum_c (EP+qi)(EP+kj), reduce over 4 lane-groups
  const float* qrow = nqvpb + ((size_t)(b * NN) + i) * DM;
  const float scale = 0.17677669529663687f;  // 1/sqrt(32)
#pragma unroll
  for (int a = 0; a < 2; ++a) {
    float s0 = 0.f, s1 = 0.f;
#pragma unroll
    for (int u = 0; u < 2; ++u) {
      int ct = a * 2 + u;
      int cbase = w * 64 + ct * 16 + ((l >> 4) * 4);
      f32x4 qi = *(const f32x4*)(qrow + cbase);
      f32x4 k0 = *(const f32x4*)(nlds + (l & 15) * 260 + cbase);
      f32x4 k1 = *(const f32x4*)(nlds + (16 + (l & 15)) * 260 + cbase);
#pragma unroll
      for (int rr = 0; rr < 4; ++rr) {
        s0 += (acc[ct][0][rr] + qi[rr]) * (acc[ct][0][rr] + k0[rr]);
        s1 += (acc[ct][1][rr] + qi[rr]) * (acc[ct][1][rr] + k1[rr]);
      }
    }
#pragma unroll
    for (int jt = 0; jt < 2; ++jt) {
      float sv = jt ? s1 : s0;
      sv += __shfl_xor(sv, 16, 64);
      sv += __shfl_xor(sv, 32, 64);
      float sc = 10.0f * tanhf(sv * scale);
      if (l < 16) {
        int h = w * 2 + a;
        int jg = j0 + jt * 16 + l;
        scores[(((size_t)(b * NH) + h) * NN + i) * NN + jg] = sc;
      }
    }
  }
}

// ---- fused softmax + attn@V + out-proj + residual + LN --------------------
__global__ __launch_bounds__(1024) void k_attn_out(
    const float* __restrict__ scores, const float* __restrict__ nqv,
    const float* __restrict__ W, const float* __restrict__ bias,
    const float* __restrict__ xs, const float* __restrict__ ln_g,
    const float* __restrict__ ln_b, float* __restrict__ ys) {
  __shared__ float sp[NH * NN];
  __shared__ float pp[4][256];
  __shared__ float aor[256];
  __shared__ float rs[4], rq[4];
  const int t = threadIdx.x;
  const int b = blockIdx.x >> 8, i = blockIdx.x & 255;
#pragma unroll
  for (int p = 0; p < 2; ++p) {
    int idx2 = p * 1024 + t;
    sp[idx2] = scores[(((size_t)(b * NH) + (idx2 >> 8)) * NN + i) * NN + (idx2 & 255)];
  }
  __syncthreads();
  const int w = t >> 6, l = t & 63;
  if (w < 8) {
    f32x4 v = *(f32x4*)(sp + w * NN + l * 4);
    float m = fmaxf(fmaxf(v[0], v[1]), fmaxf(v[2], v[3]));
#pragma unroll
    for (int mm = 1; mm <= 32; mm <<= 1) m = fmaxf(m, __shfl_xor(m, mm, 64));
    v[0] = __expf(v[0] - m); v[1] = __expf(v[1] - m);
    v[2] = __expf(v[2] - m); v[3] = __expf(v[3] - m);
    float s = v[0] + v[1] + v[2] + v[3];
#pragma unroll
    for (int mm = 1; mm <= 32; mm <<= 1) s += __shfl_xor(s, mm, 64);
    float inv = 1.0f / s;
    v[0] *= inv; v[1] *= inv; v[2] *= inv; v[3] *= inv;
    *(f32x4*)(sp + w * NN + l * 4) = v;
  }
  __syncthreads();
  const int d = t & 255, kg = t >> 8, h = d >> 5;
  const float* vb = nqv + (size_t)b * NN * DM;
  float acc = 0.f;
#pragma unroll 8
  for (int jj = 0; jj < 64; ++jj) {
    int j = kg * 64 + jj;
    acc += sp[h * 256 + j] * vb[(size_t)j * DM + d];
  }
  pp[kg][d] = acc;
  __syncthreads();
  if (t < 256) aor[t] = pp[0][t] + pp[1][t] + pp[2][t] + pp[3][t];
  __syncthreads();
  float a0 = 0.f;
#pragma unroll 8
  for (int kk = 0; kk < 64; ++kk) {
    int k = kg * 64 + kk;
    a0 += aor[k] * W[(size_t)k * DM + d];
  }
  pp[kg][d] = a0;
  __syncthreads();
  float val = 0.f;
  if (t < 256)
    val = pp[0][t] + pp[1][t] + pp[2][t] + pp[3][t] + bias[t] +
          xs[((size_t)(b * NN) + i) * DM + t];
  float s2 = val, q2 = val * val;
#pragma unroll
  for (int m = 1; m <= 32; m <<= 1) {
    s2 += __shfl_xor(s2, m, 64);
    q2 += __shfl_xor(q2, m, 64);
  }
  if (t < 256 && l == 0) { rs[w] = s2; rq[w] = q2; }
  __syncthreads();
  if (t < 256) {
    float ss = rs[0] + rs[1] + rs[2] + rs[3];
    float qq = rq[0] + rq[1] + rq[2] + rq[3];
    float mu = ss * (1.f / DM);
    float var = qq * (1.f / DM) - mu * mu;
    ys[((size_t)(b * NN) + i) * DM + t] =
        (val - mu) * rsqrtf(var + 1e-5f) * ln_g[t] + ln_b[t];
  }
}

// ---------------- fused FFN: out = gelu(ys@W1+b1)@W2 + b2 + ys -------------
__global__ __launch_bounds__(1024) void k_ffn(const float* __restrict__ ys,
                                              const float* __restrict__ W1,
                                              const float* __restrict__ b1,
                                              const float* __restrict__ W2,
                                              const float* __restrict__ b2,
                                              float* __restrict__ out) {
  __shared__ float sy[2][DM];
  __shared__ float sg[2][1024];
  __shared__ float pp[4][2][256];
  const int t = threadIdx.x;
  const int r0 = blockIdx.x * 2;
  if (t < 512) sy[t >> 8][t & 255] = ys[(size_t)(r0 + (t >> 8)) * DM + (t & 255)];
  __syncthreads();
  float a0 = b1[t], a1 = a0;
#pragma unroll 8
  for (int k = 0; k < DM; ++k) {
    float wv = W1[(size_t)k * 1024 + t];
    a0 += sy[0][k] * wv;
    a1 += sy[1][k] * wv;
  }
  sg[0][t] = 0.5f * a0 * (1.0f + erff(a0 * 0.70710678118654752f));
  sg[1][t] = 0.5f * a1 * (1.0f + erff(a1 * 0.70710678118654752f));
  __syncthreads();
  const int kg = t >> 8, col = t & 255;
  float z0 = 0.f, z1 = 0.f;
#pragma unroll 8
  for (int kk = 0; kk < 256; ++kk) {
    int k = kg * 256 + kk;
    float wv = W2[(size_t)k * 256 + col];
    z0 += sg[0][k] * wv;
    z1 += sg[1][k] * wv;
  }
  pp[kg][0][col] = z0;
  pp[kg][1][col] = z1;
  __syncthreads();
  if (t < 512) {
    int row = t >> 8;
    float r = pp[0][row][col] + pp[1][row][col] + pp[2][row][col] +
              pp[3][row][col] + b2[col] + sy[row][col];
    out[(size_t)(r0 + row) * DM + col] = r;
  }
}

extern "C" void kernel_launch(void* const* d_in, const int* in_sizes, int n_in,
                              void* d_out, int out_size, void* d_ws, size_t ws_size,
                              hipStream_t stream) {
  const float* nodes = (const float*)d_in[0];
  const float* edges = (const float*)d_in[1];
  const float* W     = (const float*)d_in[2];
  const float* bias  = (const float*)d_in[3];
  const float* ln_g  = (const float*)d_in[4];
  const float* ln_b  = (const float*)d_in[5];
  const float* W1    = (const float*)d_in[6];
  const float* b1    = (const float*)d_in[7];
  const float* W2    = (const float*)d_in[8];
  const float* b2    = (const float*)d_in[9];
  float* out = (float*)d_out;

  char* ws = (char*)d_ws;
  float*  xs     = (float*)(ws + 0x000000);   // 512 KB
  float*  nqv    = (float*)(ws + 0x080000);   // 512 KB
  float*  nqvpb  = (float*)(ws + 0x100000);   // 512 KB
  half_t* WT16   = (half_t*)(ws + 0x180000);  // 128 KB
  float*  scores = (float*)(ws + 0x1A0000);   // 4 MB
  float*  ys     = (float*)(ws + 0x5A0000);   // 512 KB

  k_ln_proj<<<NB * NN / 2, 1024, 0, stream>>>(nodes, W, bias, ln_g, ln_b, xs, nqv, nqvpb);
  k_wt16<<<DM, 256, 0, stream>>>(W, WT16);
  k_edge_scores<<<NB * NN * (NN / JT), 256, 0, stream>>>(edges, WT16, nqvpb, scores);
  k_attn_out<<<NB * NN, 1024, 0, stream>>>(scores, nqv, W, bias, xs, ln_g, ln_b, ys);
  k_ffn<<<NB * NN / 2, 1024, 0, stream>>>(ys, W1, b1, W2, b2, out);
}